// Round 5
// baseline (479.203 us; speedup 1.0000x reference)
//
#include <hip/hip_runtime.h>
#include <math.h>

#define NT 128      // 2 waves/block
#define RPT 2       // rows per thread: grid LDS reads amortized over 2 rows
#define MAXG 1536   // known-safe (R3/R4 passed); LDS 55.3 KB
#define DELTA 0.002f  // >= 2*eps_f32(score) ~= 5.6e-4, with margin

typedef float v2f __attribute__((ext_vector_type(2)));

__global__ __launch_bounds__(NT, 1)
void e8p_quant_kernel(const float* __restrict__ X,
                      const float* __restrict__ grid_part,
                      const float* __restrict__ grid_norm,
                      const int* __restrict__ pam,
                      float* __restrict__ out,
                      int N, int G)
{
#pragma clang fp contract(off)
    __shared__ float lg[MAXG * 8];
    __shared__ float ln[MAXG];

    const float4* gp4 = reinterpret_cast<const float4*>(grid_part);
    float4* lg4w = reinterpret_cast<float4*>(lg);
    for (int j = threadIdx.x; j < G; j += NT) {
        lg4w[2 * j]     = gp4[2 * j];
        lg4w[2 * j + 1] = gp4[2 * j + 1];
        ln[j] = grid_norm[j];   // multiples of 0.25 <= 12: exact in f32
    }
    __syncthreads();

    const int rbase = blockIdx.x * (NT * RPT) + threadIdx.x;
    const float4* x4 = reinterpret_cast<const float4*>(X);

    float xf[RPT][8];
    v2f   xv[RPT][8];          // {|x+0.25| (col7-flipped), |x-0.25| (col7-flipped)}
    int   msbp[RPT], msbm[RPT], oddp_[RPT], oddm_[RPT];
    bool  act[RPT];

#pragma unroll
    for (int rr = 0; rr < RPT; ++rr) {
        int r = rbase + rr * NT;
        act[rr] = (r < N);
        int rc = act[rr] ? r : 0;
        float4 a0 = x4[2 * rc], a1 = x4[2 * rc + 1];
        float xr[8] = {a0.x, a0.y, a0.z, a0.w, a1.x, a1.y, a1.z, a1.w};
        int nbp = 0, nbm = 0;
        float xpf[8], xmf[8];
#pragma unroll
        for (int k = 0; k < 8; ++k) {
            xf[rr][k] = xr[k];
            float sp = xr[k] + 0.25f, sm = xr[k] - 0.25f;
            // sign of f32(x+-0.25) == sign in f64: near-cancel is exact (Sterbenz)
            nbp |= int(sp < 0.0f) << k;
            nbm |= int(sm < 0.0f) << k;
            xpf[k] = fabsf(sp); xmf[k] = fabsf(sm);
        }
        int op = __popc(nbp) & 1, om = __popc(nbm) & 1;
        if (op) xpf[7] = -xpf[7];
        if (om) xmf[7] = -xmf[7];
        oddp_[rr] = op; oddm_[rr] = om;
        msbp[rr] = nbp ^ (op << 7);
        msbm[rr] = nbm ^ (om << 7);
#pragma unroll
        for (int k = 0; k < 8; ++k) xv[rr][k] = (v2f){xpf[k], xmf[k]};
    }

    // f32 prefilter state per row per pass: running best, band threshold,
    // 2-slot candidate ring (slot1 = older/smaller j), evicted-max guard.
    float bestp[RPT], btp[RPT], evp[RPT], sp0[RPT], sp1[RPT];
    float bestm[RPT], btm[RPT], evm[RPT], sm0[RPT], sm1[RPT];
    int jp0[RPT], jp1[RPT], jm0[RPT], jm1[RPT];
#pragma unroll
    for (int rr = 0; rr < RPT; ++rr) {
        bestp[rr] = bestm[rr] = -3.0e38f;
        btp[rr] = btm[rr] = -3.0e38f;
        evp[rr] = evm[rr] = -3.0e38f;
        sp0[rr] = sp1[rr] = sm0[rr] = sm1[rr] = -3.0e38f;
        jp0[rr] = jp1[rr] = jm0[rr] = jm1[rr] = 0;
    }

    const float4* lg4 = reinterpret_cast<const float4*>(lg);
#pragma unroll 2
    for (int j = 0; j < G; ++j) {
        float4 ga = lg4[2 * j], gb = lg4[2 * j + 1];
        float nn = ln[j];
        v2f g0 = {ga.x, ga.x}, g1 = {ga.y, ga.y}, g2 = {ga.z, ga.z}, g3 = {ga.w, ga.w};
        v2f g4 = {gb.x, gb.x}, g5 = {gb.y, gb.y}, g6 = {gb.z, gb.z}, g7 = {gb.w, gb.w};
#pragma unroll
        for (int rr = 0; rr < RPT; ++rr) {
            v2f acc = xv[rr][0] * g0;                        // {dot_p, dot_m}
            acc = __builtin_elementwise_fma(xv[rr][1], g1, acc);
            acc = __builtin_elementwise_fma(xv[rr][2], g2, acc);
            acc = __builtin_elementwise_fma(xv[rr][3], g3, acc);
            acc = __builtin_elementwise_fma(xv[rr][4], g4, acc);
            acc = __builtin_elementwise_fma(xv[rr][5], g5, acc);
            acc = __builtin_elementwise_fma(xv[rr][6], g6, acc);
            acc = __builtin_elementwise_fma(xv[rr][7], g7, acc);
            float sp = fmaf(2.0f, acc.x, -nn);
            float sm = fmaf(2.0f, acc.y, -nn);
            if (sp >= btp[rr]) {            // in band: insert (rare per lane)
                evp[rr] = fmaxf(evp[rr], sp1[rr]);
                sp1[rr] = sp0[rr]; jp1[rr] = jp0[rr];
                sp0[rr] = sp;      jp0[rr] = j;
                bestp[rr] = fmaxf(bestp[rr], sp);
                btp[rr] = bestp[rr] - DELTA;
            }
            if (sm >= btm[rr]) {
                evm[rr] = fmaxf(evm[rr], sm1[rr]);
                sm1[rr] = sm0[rr]; jm1[rr] = jm0[rr];
                sm0[rr] = sm;      jm0[rr] = j;
                bestm[rr] = fmaxf(bestm[rr], sm);
                btm[rr] = bestm[rr] - DELTA;
            }
        }
    }

    // ---- epilogue: exact f64 resolve + encode (bit-identical to R3) ----
#pragma unroll
    for (int rr = 0; rr < RPT; ++rr) {
        if (!act[rr]) continue;
        int r = rbase + rr * NT;

        double xpd[8], xmd[8];
#pragma unroll
        for (int k = 0; k < 8; ++k) {
            double xd = (double)xf[rr][k];
            xpd[k] = fabs(xd + 0.25);   // exact in f64
            xmd[k] = fabs(xd - 0.25);
        }
        if (oddp_[rr]) xpd[7] = -xpd[7];
        if (oddm_[rr]) xmd[7] = -xmd[7];

        auto exactScore = [&](int j, const double* xd) -> double {
            float4 ga = lg4[2 * j], gb = lg4[2 * j + 1];
            double s = xd[0] * (double)ga.x;
            s = fma(xd[1], (double)ga.y, s);
            s = fma(xd[2], (double)ga.z, s);
            s = fma(xd[3], (double)ga.w, s);
            s = fma(xd[4], (double)gb.x, s);
            s = fma(xd[5], (double)gb.y, s);
            s = fma(xd[6], (double)gb.z, s);
            s = fma(xd[7], (double)gb.w, s);
            return fma(2.0, s, -(double)ln[j]);
        };

        int ip = 0, im = 0;
        float thrp = bestp[rr] - DELTA, thrm = bestm[rr] - DELTA;
        bool okp = evp[rr] < thrp;      // no in-band candidate evicted
        bool okm = evm[rr] < thrm;
        if (okp) {
            double bd = -1.0e300;
            if (sp1[rr] >= thrp) { double sd = exactScore(jp1[rr], xpd); if (sd > bd) { bd = sd; ip = jp1[rr]; } }
            if (sp0[rr] >= thrp) { double sd = exactScore(jp0[rr], xpd); if (sd > bd) { bd = sd; ip = jp0[rr]; } }
        }
        if (okm) {
            double bd = -1.0e300;
            if (sm1[rr] >= thrm) { double sd = exactScore(jm1[rr], xmd); if (sd > bd) { bd = sd; im = jm1[rr]; } }
            if (sm0[rr] >= thrm) { double sd = exactScore(jm0[rr], xmd); if (sd > bd) { bd = sd; im = jm0[rr]; } }
        }
        if (!okp || !okm) {   // sound fallback: full exact scan (~never)
            double bpd = -1.0e300, bmd = -1.0e300;
            int ipd = 0, imd = 0;
            for (int j = 0; j < G; ++j) {
                double s1 = exactScore(j, xpd);
                double s2 = exactScore(j, xmd);
                if (s1 > bpd) { bpd = s1; ipd = j; }
                if (s2 > bmd) { bmd = s2; imd = j; }
            }
            ip = ipd; im = imd;
        }

        double vp[8], vm[8];
        double errP, errM; int idxP, idxM;
        auto finish = [&](int bi, double sgn_quarter, int msb, int par,
                          double* v, double& errO, int& idxO) {
#pragma clang fp contract(off)
            float4 ga = lg4[2 * bi], gb = lg4[2 * bi + 1];
            float g[8] = {ga.x, ga.y, ga.z, ga.w, gb.x, gb.y, gb.z, gb.w};
            int gneg = 0; float sumabs = 0.0f;
#pragma unroll
            for (int k = 0; k < 8; ++k) {
                gneg |= int(g[k] < 0.0f) << k;
                sumabs += fabsf(g[k]);   // exact integer in f32
            }
            double vv[8];
#pragma unroll
            for (int k = 0; k < 8; ++k) {
                unsigned u = __float_as_uint(g[k]) ^ ((((unsigned)msb >> k) & 1u) << 31);
                double val = (double)__uint_as_float(u);
                vv[k] = val;
                v[k] = val;
            }
            double d[8];
#pragma unroll
            for (int k = 0; k < 8; ++k) {
                double xs = (double)xf[rr][k] + sgn_quarter;  // exact
                d[k] = xs - vv[k];                            // exact
            }
            double s0 = d[0]*d[0], s1 = d[1]*d[1], s2 = d[2]*d[2], s3 = d[3]*d[3];
            double s4 = d[4]*d[4], s5 = d[5]*d[5], s6 = d[6]*d[6], s7 = d[7]*d[7];
            double e = ((s0 + s1) + (s2 + s3)) + ((s4 + s5) + (s6 + s7));  // np pairwise
            errO = sqrt(e);
            int godd = ((int)(sumabs + 0.5f)) & 1;   // == grid_abs_odd[abs_idx]
            int sb = gneg ^ msb;
            int mi = (((sb >> 0) & 1) ^ par)
                   | (((sb >> 2) & 1) << 1)
                   | (((sb >> 4) & 1) << 2)
                   | (((sb >> 6) & 1) << 3)
                   | (((sb >> 1) & 1) << 4)
                   | (((sb >> 3) & 1) << 5)
                   | (((sb >> 5) & 1) << 6)
                   | ((((sb >> 7) & 1) ^ godd) << 7);
            idxO = (pam[bi] << 8) + mi;
        };

        finish(ip, +0.25, msbp[rr], 1, vp, errP, idxP);
        finish(im, -0.25, msbm[rr], 0, vm, errM, idxM);
        bool which = errP < errM;   // strict <, matches ref

        float ov[8];
#pragma unroll
        for (int k = 0; k < 8; ++k) {
            double o = which ? (vp[k] - 0.25) : (vm[k] + 0.25);  // exact in f64
            ov[k] = (float)o;
        }
        float4* o4 = reinterpret_cast<float4*>(out + (size_t)r * 8);
        o4[0] = make_float4(ov[0], ov[1], ov[2], ov[3]);
        o4[1] = make_float4(ov[4], ov[5], ov[6], ov[7]);
        out[(size_t)N * 8 + r] = (float)(which ? idxP : idxM);  // < 2^16: exact
    }
}

extern "C" void kernel_launch(void* const* d_in, const int* in_sizes, int n_in,
                              void* d_out, int out_size, void* d_ws, size_t ws_size,
                              hipStream_t stream)
{
    const float* X   = (const float*)d_in[0];
    const float* gp  = (const float*)d_in[1];
    const float* gn  = (const float*)d_in[2];
    const int*   pam = (const int*)d_in[3];
    float* out = (float*)d_out;

    int N = in_sizes[0] / 8;
    int G = in_sizes[1] / 8;
    int rows_per_block = NT * RPT;
    int blocks = (N + rows_per_block - 1) / rows_per_block;
    e8p_quant_kernel<<<blocks, NT, 0, stream>>>(X, gp, gn, pam, out, N, G);
}

// Round 6
// 379.996 us; speedup vs baseline: 1.2611x; 1.2611x over previous
//
#include <hip/hip_runtime.h>
#include <math.h>

#define NT 256

typedef float v2f __attribute__((ext_vector_type(2)));

__global__ __launch_bounds__(NT, 2)
void e8p_quant_kernel(const float* __restrict__ X,
                      const float* __restrict__ gp,
                      const float* __restrict__ gn,
                      const int* __restrict__ pam,
                      float* __restrict__ out,
                      int N, int G)
{
#pragma clang fp contract(off)
    int r = blockIdx.x * NT + threadIdx.x;
    if (r >= N) return;

    const float4* x4 = reinterpret_cast<const float4*>(X);
    float4 a0 = x4[2 * r], a1 = x4[2 * r + 1];
    float xf[8] = {a0.x, a0.y, a0.z, a0.w, a1.x, a1.y, a1.z, a1.w};

    float xpf[8], xmf[8];
    int nbp = 0, nbm = 0;
    float Sp = 0.0f, Sm = 0.0f;
#pragma unroll
    for (int k = 0; k < 8; ++k) {
        float sp = xf[k] + 0.25f, sm = xf[k] - 0.25f;
        // sign of f32(x+-0.25) == f64 sign (RN monotone, no sign flips; held R3/R4)
        nbp |= int(sp < 0.0f) << k;
        nbm |= int(sm < 0.0f) << k;
        xpf[k] = fabsf(sp); xmf[k] = fabsf(sm);
        Sp += xpf[k]; Sm += xmf[k];
    }
    int oddp = __popc(nbp) & 1, oddm = __popc(nbm) & 1;
    if (oddp) xpf[7] = -xpf[7];
    if (oddm) xmf[7] = -xmf[7];
    int msbp = nbp ^ (oddp << 7);
    int msbm = nbm ^ (oddm << 7);

    // Per-row certification band: per-score f32 err <= (18M+12)*2^-24 with
    // M = 3.5*sum|xs|; diff of two scores + compare slack => DELTA below.
    float Mb = 3.5f * fmaxf(Sp, Sm);
    float DELTA = fmaf(Mb, 3.0e-6f, 2.5e-5f);

    v2f xv[8];
#pragma unroll
    for (int k = 0; k < 8; ++k) xv[k] = (v2f){xpf[k], xmf[k]};

    // f32 scan: best / second-best / first-argmax per pass.
    float bestp = -3.0e38f, best2p = -3.0e38f;
    float bestm = -3.0e38f, best2m = -3.0e38f;
    int ip = 0, im = 0;

#pragma unroll 4
    for (int j = 0; j < G; ++j) {
        const float* g = gp + 8 * j;   // uniform address -> s_load (SMEM pipe)
        float g0 = g[0], g1 = g[1], g2 = g[2], g3 = g[3];
        float g4 = g[4], g5 = g[5], g6 = g[6], g7 = g[7];
        float nn = gn[j];
        v2f acc = xv[0] * (v2f){g0, g0};                     // {dot_p, dot_m}
        acc = __builtin_elementwise_fma(xv[1], (v2f){g1, g1}, acc);
        acc = __builtin_elementwise_fma(xv[2], (v2f){g2, g2}, acc);
        acc = __builtin_elementwise_fma(xv[3], (v2f){g3, g3}, acc);
        acc = __builtin_elementwise_fma(xv[4], (v2f){g4, g4}, acc);
        acc = __builtin_elementwise_fma(xv[5], (v2f){g5, g5}, acc);
        acc = __builtin_elementwise_fma(xv[6], (v2f){g6, g6}, acc);
        acc = __builtin_elementwise_fma(xv[7], (v2f){g7, g7}, acc);
        float sp = fmaf(2.0f, acc.x, -nn);
        float sm = fmaf(2.0f, acc.y, -nn);
        bool gtp = sp > bestp;                 // strict > : first-max-wins
        ip = gtp ? j : ip;
        best2p = fmaxf(best2p, fminf(sp, bestp));   // streaming 2nd-max
        bestp  = fmaxf(bestp, sp);
        bool gtm = sm > bestm;
        im = gtm ? j : im;
        best2m = fmaxf(best2m, fminf(sm, bestm));
        bestm  = fmaxf(bestm, sm);
    }

    // Fallback: gap too small to certify -> bit-exact full f64 scan (rare).
    bool fb = ((bestp - best2p) <= DELTA) || ((bestm - best2m) <= DELTA);
    if (fb) {
        double xpd[8], xmd[8];
#pragma unroll
        for (int k = 0; k < 8; ++k) {
            double xd = (double)xf[k];
            xpd[k] = fabs(xd + 0.25);   // exact in f64
            xmd[k] = fabs(xd - 0.25);
        }
        if (oddp) xpd[7] = -xpd[7];
        if (oddm) xmd[7] = -xmd[7];
        double bpd = -1.0e300, bmd = -1.0e300;
        int ipd = 0, imd = 0;
        for (int j = 0; j < G; ++j) {
            const float* g = gp + 8 * j;   // uniform (SMEM ignores exec mask)
            double g0 = (double)g[0], g1 = (double)g[1], g2 = (double)g[2], g3 = (double)g[3];
            double g4 = (double)g[4], g5 = (double)g[5], g6 = (double)g[6], g7 = (double)g[7];
            double nn = (double)gn[j];
            double s1 = xpd[0] * g0;
            s1 = fma(xpd[1], g1, s1); s1 = fma(xpd[2], g2, s1); s1 = fma(xpd[3], g3, s1);
            s1 = fma(xpd[4], g4, s1); s1 = fma(xpd[5], g5, s1); s1 = fma(xpd[6], g6, s1);
            s1 = fma(xpd[7], g7, s1);
            s1 = fma(2.0, s1, -nn);
            double s2 = xmd[0] * g0;
            s2 = fma(xmd[1], g1, s2); s2 = fma(xmd[2], g2, s2); s2 = fma(xmd[3], g3, s2);
            s2 = fma(xmd[4], g4, s2); s2 = fma(xmd[5], g5, s2); s2 = fma(xmd[6], g6, s2);
            s2 = fma(xmd[7], g7, s2);
            s2 = fma(2.0, s2, -nn);
            if (s1 > bpd) { bpd = s1; ipd = j; }
            if (s2 > bmd) { bmd = s2; imd = j; }
        }
        ip = ipd; im = imd;
    }

    // ---- epilogue: exact f64 err + encode (bit-identical to R3-passing) ----
    double vp[8], vm[8];
    double errP, errM; int idxP, idxM;
    auto finish = [&](int bi, double sgn_quarter, int msb, int par,
                      double* v, double& errO, int& idxO) {
#pragma clang fp contract(off)
        const float4* gq = reinterpret_cast<const float4*>(gp + 8 * bi);
        float4 ga = gq[0], gb = gq[1];
        float g[8] = {ga.x, ga.y, ga.z, ga.w, gb.x, gb.y, gb.z, gb.w};
        int gneg = 0; float sumabs = 0.0f;
#pragma unroll
        for (int k = 0; k < 8; ++k) {
            gneg |= int(g[k] < 0.0f) << k;
            sumabs += fabsf(g[k]);   // exact integer in f32
        }
        double vv[8];
#pragma unroll
        for (int k = 0; k < 8; ++k) {
            unsigned u = __float_as_uint(g[k]) ^ ((((unsigned)msb >> k) & 1u) << 31);
            double val = (double)__uint_as_float(u);
            vv[k] = val;
            v[k] = val;
        }
        double d[8];
#pragma unroll
        for (int k = 0; k < 8; ++k) {
            double xs = (double)xf[k] + sgn_quarter;  // exact
            d[k] = xs - vv[k];                        // exact
        }
        double s0 = d[0]*d[0], s1 = d[1]*d[1], s2 = d[2]*d[2], s3 = d[3]*d[3];
        double s4 = d[4]*d[4], s5 = d[5]*d[5], s6 = d[6]*d[6], s7 = d[7]*d[7];
        double e = ((s0 + s1) + (s2 + s3)) + ((s4 + s5) + (s6 + s7));  // np pairwise
        errO = sqrt(e);
        int godd = ((int)(sumabs + 0.5f)) & 1;   // == grid_abs_odd[abs_idx]
        int sb = gneg ^ msb;
        int mi = (((sb >> 0) & 1) ^ par)
               | (((sb >> 2) & 1) << 1)
               | (((sb >> 4) & 1) << 2)
               | (((sb >> 6) & 1) << 3)
               | (((sb >> 1) & 1) << 4)
               | (((sb >> 3) & 1) << 5)
               | (((sb >> 5) & 1) << 6)
               | ((((sb >> 7) & 1) ^ godd) << 7);
        idxO = (pam[bi] << 8) + mi;
    };

    finish(ip, +0.25, msbp, 1, vp, errP, idxP);
    finish(im, -0.25, msbm, 0, vm, errM, idxM);
    bool which = errP < errM;   // strict <, matches ref

    float ov[8];
#pragma unroll
    for (int k = 0; k < 8; ++k) {
        double o = which ? (vp[k] - 0.25) : (vm[k] + 0.25);  // exact in f64
        ov[k] = (float)o;
    }
    float4* o4 = reinterpret_cast<float4*>(out + (size_t)r * 8);
    o4[0] = make_float4(ov[0], ov[1], ov[2], ov[3]);
    o4[1] = make_float4(ov[4], ov[5], ov[6], ov[7]);
    out[(size_t)N * 8 + r] = (float)(which ? idxP : idxM);  // < 2^16: exact
}

extern "C" void kernel_launch(void* const* d_in, const int* in_sizes, int n_in,
                              void* d_out, int out_size, void* d_ws, size_t ws_size,
                              hipStream_t stream)
{
    const float* X   = (const float*)d_in[0];
    const float* gp  = (const float*)d_in[1];
    const float* gn  = (const float*)d_in[2];
    const int*   pam = (const int*)d_in[3];
    float* out = (float*)d_out;

    int N = in_sizes[0] / 8;
    int G = in_sizes[1] / 8;
    int blocks = (N + NT - 1) / NT;
    e8p_quant_kernel<<<blocks, NT, 0, stream>>>(X, gp, gn, pam, out, N, G);
}

// Round 7
// 172.716 us; speedup vs baseline: 2.7745x; 2.2001x over previous
//
#include <hip/hip_runtime.h>
#include <math.h>

#define NT   256
#define ROWS 64
#define NW   4
#define MAXG 1536   // G ~= 1366; LDS = 1536*16 + 1536*4 + 8192 = 38.9 KB -> 4 blocks/CU

typedef _Float16 h8 __attribute__((ext_vector_type(8)));
typedef float    v2f __attribute__((ext_vector_type(2)));

__global__ __launch_bounds__(NT, 4)
void e8p_quant_kernel(const float* __restrict__ X,
                      const float* __restrict__ gp,
                      const float* __restrict__ gn,
                      const int* __restrict__ pam,
                      float* __restrict__ out,
                      int N, int G)
{
#pragma clang fp contract(off)
    __shared__ h8     lgh[MAXG];           // grid as f16: values +-{0.5..3.5} exact
    __shared__ float  ln[MAXG];            // norms f32 (multiples of 0.25: exact)
    __shared__ float4 comb[2][ROWS][NW];   // per pass/row/chunk: {s0, s1, ev, pk(i0,i1)}

    // ---- stage grid (f32 -> f16, exact) ----
    const float4* gp4 = reinterpret_cast<const float4*>(gp);
    for (int j = threadIdx.x; j < G; j += NT) {
        float4 a = gp4[2 * j], b = gp4[2 * j + 1];
        h8 h;
        h[0] = (_Float16)a.x; h[1] = (_Float16)a.y;
        h[2] = (_Float16)a.z; h[3] = (_Float16)a.w;
        h[4] = (_Float16)b.x; h[5] = (_Float16)b.y;
        h[6] = (_Float16)b.z; h[7] = (_Float16)b.w;
        lgh[j] = h;
        ln[j] = gn[j];
    }
    __syncthreads();

    const int l = threadIdx.x & (ROWS - 1);   // row lane
    const int w = threadIdx.x / ROWS;         // grid chunk
    const int r = blockIdx.x * ROWS + l;
    const int rc = (r < N) ? r : (N - 1);     // clamped compute; writes guarded later

    const float4* x4 = reinterpret_cast<const float4*>(X);
    float4 a0 = x4[2 * rc], a1 = x4[2 * rc + 1];
    float xf[8] = {a0.x, a0.y, a0.z, a0.w, a1.x, a1.y, a1.z, a1.w};

    float xpf[8], xmf[8];
    int nbp = 0, nbm = 0;
    float Sp = 0.0f, Sm = 0.0f;
#pragma unroll
    for (int k = 0; k < 8; ++k) {
        float sp = xf[k] + 0.25f, sm = xf[k] - 0.25f;
        // f32 sign == f64 sign (near-cancel exact by Sterbenz; held R3-R6)
        nbp |= int(sp < 0.0f) << k;
        nbm |= int(sm < 0.0f) << k;
        xpf[k] = fabsf(sp); xmf[k] = fabsf(sm);
        Sp += xpf[k]; Sm += xmf[k];
    }
    const int oddp = __popc(nbp) & 1, oddm = __popc(nbm) & 1;
    if (oddp) xpf[7] = -xpf[7];
    if (oddm) xmf[7] = -xmf[7];
    const int msbp = nbp ^ (oddp << 7);
    const int msbm = nbm ^ (oddm << 7);

    // per-row certification band (R6-proven): bounds |f32 score - exact score|*2
    const float Mb = 3.5f * fmaxf(Sp, Sm);
    const float DELTA = fmaf(Mb, 3.0e-6f, 2.5e-5f);

    v2f xv[8];
#pragma unroll
    for (int k = 0; k < 8; ++k) xv[k] = (v2f){xpf[k], xmf[k]};

    // ---- f32 scan of this wave's grid chunk: ring-2 + evicted-max guard ----
    const int Q = (G + NW - 1) / NW;
    const int jbeg = w * Q;
    const int jend = min(G, jbeg + Q);

    float btp = -3.0e38f, evp = -3.0e38f, sp0v = -3.0e38f, sp1v = -3.0e38f;
    float btm = -3.0e38f, evm = -3.0e38f, sm0v = -3.0e38f, sm1v = -3.0e38f;
    float bestp = -3.0e38f, bestm = -3.0e38f;
    int ip0 = 0, ip1 = 0, im0 = 0, im1 = 0;

#pragma unroll 2
    for (int j = jbeg; j < jend; ++j) {
        h8 hv = lgh[j];                       // one ds_read_b128, wave-broadcast
        float nn = ln[j];
        float g0 = (float)hv[0], g1 = (float)hv[1], g2 = (float)hv[2], g3 = (float)hv[3];
        float g4 = (float)hv[4], g5 = (float)hv[5], g6 = (float)hv[6], g7 = (float)hv[7];
        v2f acc = xv[0] * (v2f){g0, g0};      // {dot_p, dot_m}
        acc = __builtin_elementwise_fma(xv[1], (v2f){g1, g1}, acc);
        acc = __builtin_elementwise_fma(xv[2], (v2f){g2, g2}, acc);
        acc = __builtin_elementwise_fma(xv[3], (v2f){g3, g3}, acc);
        acc = __builtin_elementwise_fma(xv[4], (v2f){g4, g4}, acc);
        acc = __builtin_elementwise_fma(xv[5], (v2f){g5, g5}, acc);
        acc = __builtin_elementwise_fma(xv[6], (v2f){g6, g6}, acc);
        acc = __builtin_elementwise_fma(xv[7], (v2f){g7, g7}, acc);
        float sp = fmaf(2.0f, acc.x, -nn);
        float sm = fmaf(2.0f, acc.y, -nn);
        if (sp >= btp) {                      // in-band insert (rare per lane)
            evp = fmaxf(evp, sp1v);
            sp1v = sp0v; ip1 = ip0;
            sp0v = sp;   ip0 = j;
            bestp = fmaxf(bestp, sp);
            btp = bestp - DELTA;
        }
        if (sm >= btm) {
            evm = fmaxf(evm, sm1v);
            sm1v = sm0v; im1 = im0;
            sm0v = sm;   im0 = j;
            bestm = fmaxf(bestm, sm);
            btm = bestm - DELTA;
        }
    }

    comb[0][l][w] = make_float4(sp0v, sp1v, evp, __int_as_float(ip0 | (ip1 << 16)));
    comb[1][l][w] = make_float4(sm0v, sm1v, evm, __int_as_float(im0 | (im1 << 16)));
    __syncthreads();

    // ---- epilogue: wave 0 merges chunks, exact f64 resolve + encode ----
    if (threadIdx.x < ROWS && r < N) {
        double xpd[8], xmd[8];
#pragma unroll
        for (int k = 0; k < 8; ++k) {
            double xd = (double)xf[k];
            xpd[k] = fabs(xd + 0.25);   // exact in f64
            xmd[k] = fabs(xd - 0.25);
        }
        if (oddp) xpd[7] = -xpd[7];
        if (oddm) xmd[7] = -xmd[7];

        auto exactScore = [&](int j, const double* xd) -> double {
            h8 hv = lgh[j];             // f16 -> f32 -> f64 exact
            double s = xd[0] * (double)(float)hv[0];
            s = fma(xd[1], (double)(float)hv[1], s);
            s = fma(xd[2], (double)(float)hv[2], s);
            s = fma(xd[3], (double)(float)hv[3], s);
            s = fma(xd[4], (double)(float)hv[4], s);
            s = fma(xd[5], (double)(float)hv[5], s);
            s = fma(xd[6], (double)(float)hv[6], s);
            s = fma(xd[7], (double)(float)hv[7], s);
            return fma(2.0, s, -(double)ln[j]);
        };

        auto resolve = [&](int pp, const double* xd) -> int {
            float4 c0 = comb[pp][l][0], c1 = comb[pp][l][1];
            float4 c2 = comb[pp][l][2], c3 = comb[pp][l][3];
            float B = fmaxf(fmaxf(fmaxf(c0.x, fmaxf(c0.y, c0.z)),
                                  fmaxf(c1.x, fmaxf(c1.y, c1.z))),
                            fmaxf(fmaxf(c2.x, fmaxf(c2.y, c2.z)),
                                  fmaxf(c3.x, fmaxf(c3.y, c3.z))));
            float thr = B - DELTA;
            bool ok = (c0.z < thr) && (c1.z < thr) && (c2.z < thr) && (c3.z < thr);
            if (ok) {
                double bd = -1.0e300; int bi = 0;
                float4 cc[NW] = {c0, c1, c2, c3};
#pragma unroll
                for (int w2 = 0; w2 < NW; ++w2) {   // ascending j: i1 older than i0
                    int pk = __float_as_int(cc[w2].w);
                    int i0 = pk & 0xffff, i1 = (pk >> 16) & 0xffff;
                    if (cc[w2].y >= thr) { double sd = exactScore(i1, xd); if (sd > bd) { bd = sd; bi = i1; } }
                    if (cc[w2].x >= thr) { double sd = exactScore(i0, xd); if (sd > bd) { bd = sd; bi = i0; } }
                }
                return bi;
            }
            // sound fallback: full exact scan (needs 3 in-band pts in one chunk; ~never)
            double bd = -1.0e300; int bi = 0;
            for (int j = 0; j < G; ++j) {
                double sd = exactScore(j, xd);
                if (sd > bd) { bd = sd; bi = j; }
            }
            return bi;
        };

        int ipw = resolve(0, xpd);
        int imw = resolve(1, xmd);

        double vp[8], vm[8];
        double errP, errM; int idxP, idxM;
        auto finish = [&](int bi, double sgn_quarter, int msb, int par,
                          double* v, double& errO, int& idxO) {
#pragma clang fp contract(off)
            h8 hv = lgh[bi];
            float g[8] = {(float)hv[0], (float)hv[1], (float)hv[2], (float)hv[3],
                          (float)hv[4], (float)hv[5], (float)hv[6], (float)hv[7]};
            int gneg = 0; float sumabs = 0.0f;
#pragma unroll
            for (int k = 0; k < 8; ++k) {
                gneg |= int(g[k] < 0.0f) << k;
                sumabs += fabsf(g[k]);   // exact integer in f32
            }
            double vv[8];
#pragma unroll
            for (int k = 0; k < 8; ++k) {
                unsigned u = __float_as_uint(g[k]) ^ ((((unsigned)msb >> k) & 1u) << 31);
                double val = (double)__uint_as_float(u);
                vv[k] = val;
                v[k] = val;
            }
            double d[8];
#pragma unroll
            for (int k = 0; k < 8; ++k) {
                double xs = (double)xf[k] + sgn_quarter;  // exact
                d[k] = xs - vv[k];                        // exact
            }
            double s0 = d[0]*d[0], s1 = d[1]*d[1], s2 = d[2]*d[2], s3 = d[3]*d[3];
            double s4 = d[4]*d[4], s5 = d[5]*d[5], s6 = d[6]*d[6], s7 = d[7]*d[7];
            double e = ((s0 + s1) + (s2 + s3)) + ((s4 + s5) + (s6 + s7));  // np pairwise
            errO = sqrt(e);
            int godd = ((int)(sumabs + 0.5f)) & 1;   // == grid_abs_odd[abs_idx]
            int sb = gneg ^ msb;
            int mi = (((sb >> 0) & 1) ^ par)
                   | (((sb >> 2) & 1) << 1)
                   | (((sb >> 4) & 1) << 2)
                   | (((sb >> 6) & 1) << 3)
                   | (((sb >> 1) & 1) << 4)
                   | (((sb >> 3) & 1) << 5)
                   | (((sb >> 5) & 1) << 6)
                   | ((((sb >> 7) & 1) ^ godd) << 7);
            idxO = (pam[bi] << 8) + mi;
        };

        finish(ipw, +0.25, msbp, 1, vp, errP, idxP);
        finish(imw, -0.25, msbm, 0, vm, errM, idxM);
        bool which = errP < errM;   // strict <, matches ref

        float ov[8];
#pragma unroll
        for (int k = 0; k < 8; ++k) {
            double o = which ? (vp[k] - 0.25) : (vm[k] + 0.25);  // exact in f64
            ov[k] = (float)o;
        }
        float4* o4 = reinterpret_cast<float4*>(out + (size_t)r * 8);
        o4[0] = make_float4(ov[0], ov[1], ov[2], ov[3]);
        o4[1] = make_float4(ov[4], ov[5], ov[6], ov[7]);
        out[(size_t)N * 8 + r] = (float)(which ? idxP : idxM);  // < 2^16: exact
    }
}

extern "C" void kernel_launch(void* const* d_in, const int* in_sizes, int n_in,
                              void* d_out, int out_size, void* d_ws, size_t ws_size,
                              hipStream_t stream)
{
    const float* X   = (const float*)d_in[0];
    const float* gp  = (const float*)d_in[1];
    const float* gn  = (const float*)d_in[2];
    const int*   pam = (const int*)d_in[3];
    float* out = (float*)d_out;

    int N = in_sizes[0] / 8;
    int G = in_sizes[1] / 8;
    int blocks = (N + ROWS - 1) / ROWS;
    e8p_quant_kernel<<<blocks, NT, 0, stream>>>(X, gp, gn, pam, out, N, G);
}

// Round 8
// 154.013 us; speedup vs baseline: 3.1114x; 1.1214x over previous
//
#include <hip/hip_runtime.h>
#include <math.h>

#define NT   256
#define ROWS 128
#define NW   4
#define MAXG 1408   // G ~= 1366; LDS total 40320 B -> 4 blocks/CU

typedef _Float16 h8 __attribute__((ext_vector_type(8)));

static __device__ __forceinline__ unsigned f16_ru(float v) {
    // f32 -> f16 rounded toward +inf (conservative for ">= thr" band tests)
    _Float16 h = (_Float16)v;
    unsigned short b;
    __builtin_memcpy(&b, &h, 2);
    if ((float)h < v) b = (b & 0x8000) ? (unsigned short)(b - 1) : (unsigned short)(b + 1);
    return (unsigned)b;
}
static __device__ __forceinline__ float f16_lo(unsigned bits) {
    unsigned short s = (unsigned short)(bits & 0xffffu);
    _Float16 h;
    __builtin_memcpy(&h, &s, 2);
    return (float)h;
}

__global__ __launch_bounds__(NT, 4)
void e8p_quant_kernel(const float* __restrict__ X,
                      const float* __restrict__ gp,
                      const float* __restrict__ gn,
                      const int* __restrict__ pam,
                      float* __restrict__ out,
                      int N, int G)
{
#pragma clang fp contract(off)
    __shared__ h8            lgh[MAXG];          // grid f16 (values +-{0.5..3.5}: exact)
    __shared__ unsigned char lnu[MAXG];          // (norm-2)*4 in [0,40]: exact u8
    __shared__ float         cb_bb[2][NW][ROWS]; // chunk best = max(s0,s1,ev), f32 exact
    __shared__ float         cb_ev[2][NW][ROWS]; // evicted-max guard, f32 exact
    __shared__ unsigned      cb_h [2][NW][ROWS]; // s0h | s1h<<16 (f16 round-up)
    __shared__ unsigned      cb_ij[2][NW][ROWS]; // i0 | i1<<16

    // ---- stage grid ----
    const float4* gp4 = reinterpret_cast<const float4*>(gp);
    for (int j = threadIdx.x; j < G; j += NT) {
        float4 a = gp4[2 * j], b = gp4[2 * j + 1];
        h8 h;
        h[0] = (_Float16)a.x; h[1] = (_Float16)a.y;
        h[2] = (_Float16)a.z; h[3] = (_Float16)a.w;
        h[4] = (_Float16)b.x; h[5] = (_Float16)b.y;
        h[6] = (_Float16)b.z; h[7] = (_Float16)b.w;
        lgh[j] = h;
        lnu[j] = (unsigned char)((gn[j] - 2.0f) * 4.0f + 0.5f);
    }
    __syncthreads();

    const int lane = threadIdx.x & 63;
    const int w    = threadIdx.x >> 6;
    const int rb   = blockIdx.x * ROWS;

    // ---- per-row prep (2 rows per lane) ----
    float xf[2][8], xp[2][8], xm[2][8];
    int msbp[2], msbm[2], oddp[2], oddm[2];
    float DLT[2];
    const float4* x4 = reinterpret_cast<const float4*>(X);
#pragma unroll
    for (int rr = 0; rr < 2; ++rr) {
        int r = rb + lane + (rr << 6);
        int rc = (r < N) ? r : (N - 1);
        float4 a0 = x4[2 * rc], a1 = x4[2 * rc + 1];
        float xr[8] = {a0.x, a0.y, a0.z, a0.w, a1.x, a1.y, a1.z, a1.w};
        int nbp = 0, nbm = 0; float Sp = 0.f, Sm = 0.f;
#pragma unroll
        for (int k = 0; k < 8; ++k) {
            xf[rr][k] = xr[k];
            float sp = xr[k] + 0.25f, sm = xr[k] - 0.25f;
            // f32 sign == f64 sign (near-cancel exact, Sterbenz; held R3-R7)
            nbp |= int(sp < 0.f) << k;  nbm |= int(sm < 0.f) << k;
            xp[rr][k] = fabsf(sp);  xm[rr][k] = fabsf(sm);
            Sp += xp[rr][k]; Sm += xm[rr][k];
        }
        int op = __popc(nbp) & 1, om = __popc(nbm) & 1;
        if (op) xp[rr][7] = -xp[rr][7];
        if (om) xm[rr][7] = -xm[rr][7];
        oddp[rr] = op; oddm[rr] = om;
        msbp[rr] = nbp ^ (op << 7);  msbm[rr] = nbm ^ (om << 7);
        // band >= 2x f32 chain error (R6/R7-proven formula, extra-conservative
        // at half-scale scores)
        DLT[rr] = fmaf(3.5f * fmaxf(Sp, Sm), 3.0e-6f, 2.5e-5f);
    }

    // ring-2 + evicted-max state [row][pass]
    float bt[2][2], ev[2][2], s0[2][2], s1[2][2];
    int   i0[2][2], i1[2][2];
#pragma unroll
    for (int rr = 0; rr < 2; ++rr)
#pragma unroll
        for (int pp = 0; pp < 2; ++pp) {
            bt[rr][pp] = -3.0e38f; ev[rr][pp] = -3.0e38f;
            s0[rr][pp] = -3.0e38f; s1[rr][pp] = -3.0e38f;
            i0[rr][pp] = 0; i1[rr][pp] = 0;
        }

    const int Q = (G + NW - 1) / NW;
    const int jbeg = w * Q, jend = min(G, jbeg + Q);

    // ---- f32 half-scale scan: s' = <x,g> - norm/2 (seeded chain) ----
    for (int j = jbeg; j < jend; ++j) {
        h8 hv = lgh[j];
        float nnh = fmaf(-0.125f, (float)lnu[j], -1.0f);   // = -norm/2, exact
        float g0=(float)hv[0], g1=(float)hv[1], g2=(float)hv[2], g3=(float)hv[3];
        float g4=(float)hv[4], g5=(float)hv[5], g6=(float)hv[6], g7=(float)hv[7];
#pragma unroll
        for (int rr = 0; rr < 2; ++rr) {
            float ap = fmaf(xp[rr][0], g0, nnh);
            ap = fmaf(xp[rr][1], g1, ap); ap = fmaf(xp[rr][2], g2, ap);
            ap = fmaf(xp[rr][3], g3, ap); ap = fmaf(xp[rr][4], g4, ap);
            ap = fmaf(xp[rr][5], g5, ap); ap = fmaf(xp[rr][6], g6, ap);
            ap = fmaf(xp[rr][7], g7, ap);
            float am = fmaf(xm[rr][0], g0, nnh);
            am = fmaf(xm[rr][1], g1, am); am = fmaf(xm[rr][2], g2, am);
            am = fmaf(xm[rr][3], g3, am); am = fmaf(xm[rr][4], g4, am);
            am = fmaf(xm[rr][5], g5, am); am = fmaf(xm[rr][6], g6, am);
            am = fmaf(xm[rr][7], g7, am);
            if (ap >= bt[rr][0]) {                 // in-band insert (rare)
                ev[rr][0] = fmaxf(ev[rr][0], s1[rr][0]);
                s1[rr][0] = s0[rr][0]; i1[rr][0] = i0[rr][0];
                s0[rr][0] = ap;        i0[rr][0] = j;
                bt[rr][0] = fmaxf(bt[rr][0], ap - DLT[rr]);
            }
            if (am >= bt[rr][1]) {
                ev[rr][1] = fmaxf(ev[rr][1], s1[rr][1]);
                s1[rr][1] = s0[rr][1]; i1[rr][1] = i0[rr][1];
                s0[rr][1] = am;        i0[rr][1] = j;
                bt[rr][1] = fmaxf(bt[rr][1], am - DLT[rr]);
            }
        }
    }

#pragma unroll
    for (int rr = 0; rr < 2; ++rr) {
        int rowL = lane + (rr << 6);
#pragma unroll
        for (int pp = 0; pp < 2; ++pp) {
            cb_bb[pp][w][rowL] = fmaxf(s0[rr][pp], fmaxf(s1[rr][pp], ev[rr][pp]));
            cb_ev[pp][w][rowL] = ev[rr][pp];
            cb_h [pp][w][rowL] = f16_ru(s0[rr][pp]) | (f16_ru(s1[rr][pp]) << 16);
            cb_ij[pp][w][rowL] = (unsigned)i0[rr][pp] | ((unsigned)i1[rr][pp] << 16);
        }
    }
    __syncthreads();

    // ---- merge + exact f64 resolve + encode: threads 0..127, row = t ----
    const int t = threadIdx.x;
    if (t >= ROWS) return;
    const int row = rb + t;
    if (row >= N) return;
    const int rs = (t >= 64) ? 1 : 0;   // own-state slot holding row t

    double xpd[8], xmd[8];
#pragma unroll
    for (int k = 0; k < 8; ++k) {
        double xd = (double)xf[rs][k];
        xpd[k] = fabs(xd + 0.25);   // exact in f64
        xmd[k] = fabs(xd - 0.25);
    }
    if (oddp[rs]) xpd[7] = -xpd[7];
    if (oddm[rs]) xmd[7] = -xmd[7];

    auto exactScore = [&](int j, const double* xd) -> double {
        h8 hv = lgh[j];
        double s = xd[0] * (double)(float)hv[0];
        s = fma(xd[1], (double)(float)hv[1], s);
        s = fma(xd[2], (double)(float)hv[2], s);
        s = fma(xd[3], (double)(float)hv[3], s);
        s = fma(xd[4], (double)(float)hv[4], s);
        s = fma(xd[5], (double)(float)hv[5], s);
        s = fma(xd[6], (double)(float)hv[6], s);
        s = fma(xd[7], (double)(float)hv[7], s);
        double nn = 2.0 + 0.25 * (double)lnu[j];   // exact
        return fma(2.0, s, -nn);                   // == R3's bit-exact form
    };

    auto resolve = [&](int pp, const double* xd) -> int {
        float B = fmaxf(fmaxf(cb_bb[pp][0][t], cb_bb[pp][1][t]),
                        fmaxf(cb_bb[pp][2][t], cb_bb[pp][3][t]));
        float thr = B - DLT[rs];
        bool ok = (cb_ev[pp][0][t] < thr) && (cb_ev[pp][1][t] < thr) &&
                  (cb_ev[pp][2][t] < thr) && (cb_ev[pp][3][t] < thr);
        if (ok) {
            double bd = -1.0e300; int bi = 0;
#pragma unroll
            for (int w2 = 0; w2 < NW; ++w2) {      // ascending j: i1 older than i0
                unsigned hh = cb_h[pp][w2][t], ij = cb_ij[pp][w2][t];
                float s1f = f16_lo(hh >> 16), s0f = f16_lo(hh);
                int ii1 = (int)(ij >> 16), ii0 = (int)(ij & 0xffffu);
                if (s1f >= thr) { double sd = exactScore(ii1, xd); if (sd > bd) { bd = sd; bi = ii1; } }
                if (s0f >= thr) { double sd = exactScore(ii0, xd); if (sd > bd) { bd = sd; bi = ii0; } }
            }
            return bi;
        }
        // sound fallback: full exact scan (needs 3 in-band pts in one chunk)
        double bd = -1.0e300; int bi = 0;
        for (int j = 0; j < G; ++j) {
            double sd = exactScore(j, xd);
            if (sd > bd) { bd = sd; bi = j; }
        }
        return bi;
    };

    int ipw = resolve(0, xpd);
    int imw = resolve(1, xmd);

    double vp[8], vm[8];
    double errP, errM; int idxP, idxM;
    auto finish = [&](int bi, double sgn_quarter, int msb, int par,
                      double* v, double& errO, int& idxO) {
#pragma clang fp contract(off)
        h8 hv = lgh[bi];
        float g[8] = {(float)hv[0], (float)hv[1], (float)hv[2], (float)hv[3],
                      (float)hv[4], (float)hv[5], (float)hv[6], (float)hv[7]};
        int gneg = 0; float sumabs = 0.0f;
#pragma unroll
        for (int k = 0; k < 8; ++k) {
            gneg |= int(g[k] < 0.0f) << k;
            sumabs += fabsf(g[k]);   // exact integer in f32
        }
        double vv[8];
#pragma unroll
        for (int k = 0; k < 8; ++k) {
            unsigned u = __float_as_uint(g[k]) ^ ((((unsigned)msb >> k) & 1u) << 31);
            double val = (double)__uint_as_float(u);
            vv[k] = val;
            v[k] = val;
        }
        double d[8];
#pragma unroll
        for (int k = 0; k < 8; ++k) {
            double xs = (double)xf[rs][k] + sgn_quarter;  // exact
            d[k] = xs - vv[k];                            // exact
        }
        double q0 = d[0]*d[0], q1 = d[1]*d[1], q2 = d[2]*d[2], q3 = d[3]*d[3];
        double q4 = d[4]*d[4], q5 = d[5]*d[5], q6 = d[6]*d[6], q7 = d[7]*d[7];
        double e = ((q0 + q1) + (q2 + q3)) + ((q4 + q5) + (q6 + q7));  // np pairwise
        errO = sqrt(e);
        int godd = ((int)(sumabs + 0.5f)) & 1;   // == grid_abs_odd[abs_idx]
        int sb = gneg ^ msb;
        int mi = (((sb >> 0) & 1) ^ par)
               | (((sb >> 2) & 1) << 1)
               | (((sb >> 4) & 1) << 2)
               | (((sb >> 6) & 1) << 3)
               | (((sb >> 1) & 1) << 4)
               | (((sb >> 3) & 1) << 5)
               | (((sb >> 5) & 1) << 6)
               | ((((sb >> 7) & 1) ^ godd) << 7);
        idxO = (pam[bi] << 8) + mi;
    };

    finish(ipw, +0.25, msbp[rs], 1, vp, errP, idxP);
    finish(imw, -0.25, msbm[rs], 0, vm, errM, idxM);
    bool which = errP < errM;   // strict <, matches ref

    float ov[8];
#pragma unroll
    for (int k = 0; k < 8; ++k) {
        double o = which ? (vp[k] - 0.25) : (vm[k] + 0.25);  // exact in f64
        ov[k] = (float)o;
    }
    float4* o4 = reinterpret_cast<float4*>(out + (size_t)row * 8);
    o4[0] = make_float4(ov[0], ov[1], ov[2], ov[3]);
    o4[1] = make_float4(ov[4], ov[5], ov[6], ov[7]);
    out[(size_t)N * 8 + row] = (float)(which ? idxP : idxM);  // < 2^16: exact
}

extern "C" void kernel_launch(void* const* d_in, const int* in_sizes, int n_in,
                              void* d_out, int out_size, void* d_ws, size_t ws_size,
                              hipStream_t stream)
{
    const float* X   = (const float*)d_in[0];
    const float* gp  = (const float*)d_in[1];
    const float* gn  = (const float*)d_in[2];
    const int*   pam = (const int*)d_in[3];
    float* out = (float*)d_out;

    int N = in_sizes[0] / 8;
    int G = in_sizes[1] / 8;
    int blocks = (N + ROWS - 1) / ROWS;
    e8p_quant_kernel<<<blocks, NT, 0, stream>>>(X, gp, gn, pam, out, N, G);
}

// Round 9
// 74.625 us; speedup vs baseline: 6.4215x; 2.0638x over previous
//
#include <hip/hip_runtime.h>
#include <math.h>

#define NT   256
#define ROWS 128
#define NW   4
#define MAXA 320   // abs-row groups (actual 256)

typedef _Float16 h8 __attribute__((ext_vector_type(8)));

static __device__ __forceinline__ unsigned f16_ru(float v) {
    // f32 -> f16 rounded toward +inf (conservative for ">= thr" band tests)
    _Float16 h = (_Float16)v;
    unsigned short b;
    __builtin_memcpy(&b, &h, 2);
    if ((float)h < v) b = (b & 0x8000) ? (unsigned short)(b - 1) : (unsigned short)(b + 1);
    return (unsigned)b;
}
static __device__ __forceinline__ float f16_lo(unsigned bits) {
    unsigned short s = (unsigned short)(bits & 0xffffu);
    _Float16 h;
    __builtin_memcpy(&h, &s, 2);
    return (float)h;
}

__global__ __launch_bounds__(NT, 4)
void e8p_quant_kernel(const float* __restrict__ X,
                      const float* __restrict__ gp,
                      const float* __restrict__ gn,
                      const int* __restrict__ pam,
                      float* __restrict__ out,
                      int N, int G)
{
#pragma clang fp contract(off)
    __shared__ h8             labs[MAXA];    // group base vector, f16 (exact)
    __shared__ unsigned short lmeta[MAXA];   // halfmask | (normcode<<8)
    __shared__ unsigned short lj0[MAXA];     // group start j
    __shared__ float    cb_bb[2][NW][ROWS];  // chunk best estimate (f32)
    __shared__ float    cb_ev[2][NW][ROWS];  // evicted-max guard (f32)
    __shared__ unsigned cb_h [2][NW][ROWS];  // rowmax s0,s1 as f16 round-up
    __shared__ unsigned cb_ij[2][NW][ROWS];  // row ids i0 | i1<<16

    const int NG = pam[G - 1] + 1;           // group count (=256)

    // ---- stage group table from pam transitions ----
    const float4* gp4 = reinterpret_cast<const float4*>(gp);
    for (int j = threadIdx.x; j < G; j += NT) {
        int a = pam[j];
        bool st = (j == 0) || (pam[j - 1] != a);
        if (st) {
            float4 A = gp4[2 * j], B = gp4[2 * j + 1];
            float gv[8] = {A.x, A.y, A.z, A.w, B.x, B.y, B.z, B.w};
            h8 h;
#pragma unroll
            for (int k = 0; k < 8; ++k) h[k] = (_Float16)gv[k];
            labs[a] = h;
            int hm = 0;
#pragma unroll
            for (int k = 0; k < 7; ++k) hm |= int(fabsf(gv[k]) == 0.5f) << k;
            int nc = (int)((gn[j] - 2.0f) * 4.0f + 0.5f);   // (norm-2)*4 in [0,40]
            lmeta[a] = (unsigned short)(hm | (nc << 8));
            lj0[a] = (unsigned short)j;
        }
    }
    __syncthreads();

    const int lane = threadIdx.x & 63;
    const int w    = threadIdx.x >> 6;
    const int rb   = blockIdx.x * ROWS;

    // ---- per-row prep (2 rows per lane) ----
    float xf[2][8], xp[2][8], xm[2][8];
    int msbp[2], msbm[2], oddp[2], oddm[2];
    float DLT[2];
    const float4* x4 = reinterpret_cast<const float4*>(X);
#pragma unroll
    for (int rr = 0; rr < 2; ++rr) {
        int r = rb + lane + (rr << 6);
        int rc = (r < N) ? r : (N - 1);
        float4 a0 = x4[2 * rc], a1 = x4[2 * rc + 1];
        float xr[8] = {a0.x, a0.y, a0.z, a0.w, a1.x, a1.y, a1.z, a1.w};
        int nbp = 0, nbm = 0; float Sp = 0.f, Sm = 0.f;
#pragma unroll
        for (int k = 0; k < 8; ++k) {
            xf[rr][k] = xr[k];
            float sp = xr[k] + 0.25f, sm = xr[k] - 0.25f;
            // f32 sign == f64 sign (near-cancel exact, Sterbenz; held R3-R8)
            nbp |= int(sp < 0.f) << k;  nbm |= int(sm < 0.f) << k;
            xp[rr][k] = fabsf(sp);  xm[rr][k] = fabsf(sm);
            Sp += xp[rr][k]; Sm += xm[rr][k];
        }
        int op = __popc(nbp) & 1, om = __popc(nbm) & 1;
        if (op) xp[rr][7] = -xp[rr][7];
        if (om) xm[rr][7] = -xm[rr][7];
        oddp[rr] = op; oddm[rr] = om;
        msbp[rr] = nbp ^ (op << 7);  msbm[rr] = nbm ^ (om << 7);
        // full-scale error band applied to half-scale scores: 2x extra margin
        DLT[rr] = fmaf(3.5f * fmaxf(Sp, Sm), 3.0e-6f, 2.5e-5f);
    }

    // ring-2 + evicted-max state over GROUPS [row][pass]
    float bt[2][2], ev[2][2], s0v[2][2], s1v[2][2];
    int   i0[2][2], i1[2][2];
#pragma unroll
    for (int rr = 0; rr < 2; ++rr)
#pragma unroll
        for (int pp = 0; pp < 2; ++pp) {
            bt[rr][pp] = -3.0e38f; ev[rr][pp] = -3.0e38f;
            s0v[rr][pp] = -3.0e38f; s1v[rr][pp] = -3.0e38f;
            i0[rr][pp] = 0; i1[rr][pp] = 0;
        }

    const int Q = (NG + NW - 1) / NW;
    const int abeg = w * Q, aend = min(NG, abeg + Q);

    // ---- group scan: half-scale base score + rank-1 variant maxima ----
    for (int a = abeg; a < aend; ++a) {
        h8 hv = labs[a];
        int meta = __builtin_amdgcn_readfirstlane((int)lmeta[a]);  // wave-uniform
        int hm = meta & 0x7f;
        float nnh = fmaf(-0.125f, (float)(meta >> 8), -1.0f);      // = -norm/2
        float g0=(float)hv[0], g1=(float)hv[1], g2=(float)hv[2], g3=(float)hv[3];
        float g4=(float)hv[4], g5=(float)hv[5], g6=(float)hv[6], g7=(float)hv[7];
        float m2c7 = -2.0f * g7;

        float sc[2][2], wv[2][2], rm[2][2];
#pragma unroll
        for (int rr = 0; rr < 2; ++rr) {
            float s = fmaf(xp[rr][0], g0, nnh);
            s = fmaf(xp[rr][1], g1, s); s = fmaf(xp[rr][2], g2, s);
            s = fmaf(xp[rr][3], g3, s); s = fmaf(xp[rr][4], g4, s);
            s = fmaf(xp[rr][5], g5, s); s = fmaf(xp[rr][6], g6, s);
            s = fmaf(xp[rr][7], g7, s);
            sc[rr][0] = s;
            float t = fmaf(xm[rr][0], g0, nnh);
            t = fmaf(xm[rr][1], g1, t); t = fmaf(xm[rr][2], g2, t);
            t = fmaf(xm[rr][3], g3, t); t = fmaf(xm[rr][4], g4, t);
            t = fmaf(xm[rr][5], g5, t); t = fmaf(xm[rr][6], g6, t);
            t = fmaf(xm[rr][7], g7, t);
            sc[rr][1] = t;
            wv[rr][0] = fmaf(m2c7, xp[rr][7], s);   // base + col7-flip term
            wv[rr][1] = fmaf(m2c7, xm[rr][7], t);
            rm[rr][0] = s; rm[rr][1] = t;
        }
#pragma unroll
        for (int i = 0; i < 7; ++i) {
            if (hm & (1 << i)) {    // wave-uniform scalar branch
                rm[0][0] = fmaxf(rm[0][0], wv[0][0] - xp[0][i]);
                rm[0][1] = fmaxf(rm[0][1], wv[0][1] - xm[0][i]);
                rm[1][0] = fmaxf(rm[1][0], wv[1][0] - xp[1][i]);
                rm[1][1] = fmaxf(rm[1][1], wv[1][1] - xm[1][i]);
            }
        }
#pragma unroll
        for (int rr = 0; rr < 2; ++rr)
#pragma unroll
            for (int pp = 0; pp < 2; ++pp) {
                float v = rm[rr][pp];
                if (v >= bt[rr][pp]) {              // in-band insert (rare)
                    ev[rr][pp] = fmaxf(ev[rr][pp], s1v[rr][pp]);
                    s1v[rr][pp] = s0v[rr][pp]; i1[rr][pp] = i0[rr][pp];
                    s0v[rr][pp] = v;           i0[rr][pp] = a;
                    bt[rr][pp] = fmaxf(bt[rr][pp], v - DLT[rr]);
                }
            }
    }

#pragma unroll
    for (int rr = 0; rr < 2; ++rr) {
        int rowL = lane + (rr << 6);
#pragma unroll
        for (int pp = 0; pp < 2; ++pp) {
            cb_bb[pp][w][rowL] = fmaxf(s0v[rr][pp], fmaxf(s1v[rr][pp], ev[rr][pp]));
            cb_ev[pp][w][rowL] = ev[rr][pp];
            cb_h [pp][w][rowL] = f16_ru(s0v[rr][pp]) | (f16_ru(s1v[rr][pp]) << 16);
            cb_ij[pp][w][rowL] = (unsigned)i0[rr][pp] | ((unsigned)i1[rr][pp] << 16);
        }
    }
    __syncthreads();

    // ---- merge + exact f64 resolve + encode: threads 0..127 ----
    const int t = threadIdx.x;
    if (t >= ROWS) return;
    const int row = rb + t;
    if (row >= N) return;
    const int rs = (t >= 64) ? 1 : 0;

    double xpd[8], xmd[8];
#pragma unroll
    for (int k = 0; k < 8; ++k) {
        double xd = (double)xf[rs][k];
        xpd[k] = fabs(xd + 0.25);   // exact in f64
        xmd[k] = fabs(xd - 0.25);
    }
    if (oddp[rs]) xpd[7] = -xpd[7];
    if (oddm[rs]) xmd[7] = -xmd[7];

    // exact full-scale evaluation of every variant of group a, ascending j
    auto evalRow = [&](int a, const double* xd, double& bd, int& brow, int& bflip) {
        h8 hv = labs[a];
        int meta = (int)lmeta[a];
        int hm = meta & 0x7f;
        double nd = 2.0 + 0.25 * (double)(meta >> 8);   // exact norm
        double a0=(double)(float)hv[0], a1=(double)(float)hv[1];
        double a2=(double)(float)hv[2], a3=(double)(float)hv[3];
        double a4=(double)(float)hv[4], a5=(double)(float)hv[5];
        double a6=(double)(float)hv[6], a7=(double)(float)hv[7];
        double s = xd[0] * a0;
        s = fma(xd[1], a1, s); s = fma(xd[2], a2, s); s = fma(xd[3], a3, s);
        s = fma(xd[4], a4, s); s = fma(xd[5], a5, s); s = fma(xd[6], a6, s);
        s = fma(xd[7], a7, s);
        double sc0 = fma(2.0, s, -nd);                  // exact
        if (sc0 > bd) { bd = sc0; brow = a; bflip = -1; }
        double sb2 = sc0 - 4.0 * (xd[7] * a7);          // exact (dyadic)
#pragma unroll
        for (int i = 0; i < 7; ++i) {
            if (hm & (1 << i)) {
                double sv = sb2 - 2.0 * xd[i];          // exact
                if (sv > bd) { bd = sv; brow = a; bflip = i; }
            }
        }
    };

    auto resolve = [&](int pp, const double* xd, int& browO, int& bflipO) {
        float B = fmaxf(fmaxf(cb_bb[pp][0][t], cb_bb[pp][1][t]),
                        fmaxf(cb_bb[pp][2][t], cb_bb[pp][3][t]));
        float thr = B - DLT[rs];
        bool ok = (cb_ev[pp][0][t] < thr) && (cb_ev[pp][1][t] < thr) &&
                  (cb_ev[pp][2][t] < thr) && (cb_ev[pp][3][t] < thr);
        double bd = -1.0e300; int brow = 0, bflip = -1;
        if (ok) {
#pragma unroll
            for (int w2 = 0; w2 < NW; ++w2) {   // ascending rows: i1 older than i0
                unsigned hh = cb_h[pp][w2][t], ij = cb_ij[pp][w2][t];
                if (f16_lo(hh >> 16) >= thr) evalRow((int)(ij >> 16), xd, bd, brow, bflip);
                if (f16_lo(hh & 0xffffu) >= thr) evalRow((int)(ij & 0xffffu), xd, bd, brow, bflip);
            }
        } else {
            // sound fallback: exact scan over all groups (ascending j)
            for (int a = 0; a < NG; ++a) evalRow(a, xd, bd, brow, bflip);
        }
        browO = brow; bflipO = bflip;
    };

    int prow, pflip, mrow, mflip;
    resolve(0, xpd, prow, pflip);
    resolve(1, xmd, mrow, mflip);

    double vp[8], vm[8];
    double errP, errM; int idxP, idxM;
    auto finish = [&](int brow, int bflip, double sgn_quarter, int msb, int par,
                      double* v, double& errO, int& idxO) {
#pragma clang fp contract(off)
        h8 hv = labs[brow];
        float g[8];
#pragma unroll
        for (int k = 0; k < 8; ++k) g[k] = (float)hv[k];
        if (bflip >= 0) {
#pragma unroll
            for (int k = 0; k < 7; ++k) if (bflip == k) g[k] = -g[k];
            g[7] = -g[7];
        }
        int gneg = 0; float sumabs = 0.0f;
#pragma unroll
        for (int k = 0; k < 8; ++k) {
            gneg |= int(g[k] < 0.0f) << k;
            sumabs += fabsf(g[k]);   // exact integer in f32
        }
        double vv[8];
#pragma unroll
        for (int k = 0; k < 8; ++k) {
            unsigned u = __float_as_uint(g[k]) ^ ((((unsigned)msb >> k) & 1u) << 31);
            double val = (double)__uint_as_float(u);
            vv[k] = val;
            v[k] = val;
        }
        double d[8];
#pragma unroll
        for (int k = 0; k < 8; ++k) {
            double xs = (double)xf[rs][k] + sgn_quarter;  // exact
            d[k] = xs - vv[k];                            // exact
        }
        double q0 = d[0]*d[0], q1 = d[1]*d[1], q2 = d[2]*d[2], q3 = d[3]*d[3];
        double q4 = d[4]*d[4], q5 = d[5]*d[5], q6 = d[6]*d[6], q7 = d[7]*d[7];
        double e = ((q0 + q1) + (q2 + q3)) + ((q4 + q5) + (q6 + q7));  // np pairwise
        errO = sqrt(e);
        int godd = ((int)(sumabs + 0.5f)) & 1;   // == grid_abs_odd[abs_idx]
        int sb = gneg ^ msb;
        int mi = (((sb >> 0) & 1) ^ par)
               | (((sb >> 2) & 1) << 1)
               | (((sb >> 4) & 1) << 2)
               | (((sb >> 6) & 1) << 3)
               | (((sb >> 1) & 1) << 4)
               | (((sb >> 3) & 1) << 5)
               | (((sb >> 5) & 1) << 6)
               | ((((sb >> 7) & 1) ^ godd) << 7);
        idxO = (brow << 8) + mi;                 // pam[j] == group id
    };

    finish(prow, pflip, +0.25, msbp[rs], 1, vp, errP, idxP);
    finish(mrow, mflip, -0.25, msbm[rs], 0, vm, errM, idxM);
    bool which = errP < errM;   // strict <, matches ref

    float ov[8];
#pragma unroll
    for (int k = 0; k < 8; ++k) {
        double o = which ? (vp[k] - 0.25) : (vm[k] + 0.25);  // exact in f64
        ov[k] = (float)o;
    }
    float4* o4 = reinterpret_cast<float4*>(out + (size_t)row * 8);
    o4[0] = make_float4(ov[0], ov[1], ov[2], ov[3]);
    o4[1] = make_float4(ov[4], ov[5], ov[6], ov[7]);
    out[(size_t)N * 8 + row] = (float)(which ? idxP : idxM);  // < 2^16: exact
}

extern "C" void kernel_launch(void* const* d_in, const int* in_sizes, int n_in,
                              void* d_out, int out_size, void* d_ws, size_t ws_size,
                              hipStream_t stream)
{
    const float* X   = (const float*)d_in[0];
    const float* gp  = (const float*)d_in[1];
    const float* gn  = (const float*)d_in[2];
    const int*   pam = (const int*)d_in[3];
    float* out = (float*)d_out;

    int N = in_sizes[0] / 8;
    int G = in_sizes[1] / 8;
    int blocks = (N + ROWS - 1) / ROWS;
    e8p_quant_kernel<<<blocks, NT, 0, stream>>>(X, gp, gn, pam, out, N, G);
}